// Round 7
// baseline (497.468 us; speedup 1.0000x reference)
//
#include <hip/hip_runtime.h>

#define SCAN_B 1024

// ---------------- CSR build ----------------
__global__ __launch_bounds__(256) void k_zero(int* __restrict__ cnt, int n) {
    int i = blockIdx.x * 256 + threadIdx.x;
    if (i < n) cnt[i] = 0;
}

__global__ __launch_bounds__(256) void k_hist(
    const int* __restrict__ dst_a, const int* __restrict__ dst_b,
    int* __restrict__ cnt, int n_a, int E)
{
    int i = blockIdx.x * 256 + threadIdx.x;
    if (i >= 2 * E) return;
    int idx = (i < E) ? dst_a[i] : (n_a + dst_b[i - E]);
    atomicAdd(&cnt[idx], 1);
}

__global__ __launch_bounds__(SCAN_B) void k_scan1(
    const int* __restrict__ cnt, int n, int* __restrict__ rowptr, int* __restrict__ bsum)
{
    __shared__ int tmp[SCAN_B];
    int i = blockIdx.x * SCAN_B + threadIdx.x;
    int v = (i < n) ? cnt[i] : 0;
    tmp[threadIdx.x] = v;
    __syncthreads();
    for (int off = 1; off < SCAN_B; off <<= 1) {
        int t = (threadIdx.x >= (unsigned)off) ? tmp[threadIdx.x - off] : 0;
        __syncthreads();
        tmp[threadIdx.x] += t;
        __syncthreads();
    }
    if (i < n) rowptr[i] = tmp[threadIdx.x] - v;   // exclusive
    if (threadIdx.x == SCAN_B - 1) bsum[blockIdx.x] = tmp[threadIdx.x];
}

__global__ __launch_bounds__(SCAN_B) void k_scan2(int* __restrict__ bsum, int nb) {
    __shared__ int tmp[SCAN_B];
    int i = threadIdx.x;
    int v = (i < nb) ? bsum[i] : 0;
    tmp[i] = v;
    __syncthreads();
    for (int off = 1; off < SCAN_B; off <<= 1) {
        int t = (i >= off) ? tmp[i - off] : 0;
        __syncthreads();
        tmp[i] += t;
        __syncthreads();
    }
    if (i < nb) bsum[i] = tmp[i] - v;              // exclusive
}

__global__ __launch_bounds__(256) void k_scan3(
    int* __restrict__ rowptr, int* __restrict__ cursor,
    const int* __restrict__ bsum, int n, int total)
{
    int i = blockIdx.x * 256 + threadIdx.x;
    if (i < n) {
        int r = rowptr[i] + bsum[i / SCAN_B];
        rowptr[i] = r;
        cursor[i] = r;
    }
    if (i == 0) rowptr[n] = total;
}

__global__ __launch_bounds__(256) void k_fill(
    const int* __restrict__ src_a, const int* __restrict__ dst_a,
    const int* __restrict__ src_b, const int* __restrict__ dst_b,
    int* __restrict__ cursor, int* __restrict__ sorted_src, int n_a, int E)
{
    int i = blockIdx.x * 256 + threadIdx.x;
    if (i >= 2 * E) return;
    int idx, s;
    if (i < E) { idx = dst_a[i];            s = src_a[i]; }
    else       { idx = n_a + dst_b[i - E];  s = src_b[i - E]; }
    int pos = atomicAdd(&cursor[idx], 1);
    sorted_src[pos] = s;
}

// ---------- dual GEMM, both node types in one grid --------------------------
// Per block: 128 rows x 256 cols (cols 0-127 -> Y0 via W0, 128-255 -> Y1 via W1).
// 512 threads; per-thread 8x8 tile (ratio 8 FLOP/LDS-float = 2 FLOP/B, at the
// 128 B/cyc/CU LDS roofline). X stored TRANSPOSED in LDS so A-fragments are
// b128 broadcast reads (all lanes of a half-wave hit the same address).
__global__ __launch_bounds__(512) void gemm_dual(
    const float* __restrict__ X0,
    const float* __restrict__ W00, const float* __restrict__ B00, float* __restrict__ Y00,
    const float* __restrict__ W01, const float* __restrict__ B01, float* __restrict__ Y01,
    int M0, int nb0,
    const float* __restrict__ X1,
    const float* __restrict__ W10, const float* __restrict__ B10, float* __restrict__ Y10,
    const float* __restrict__ W11, const float* __restrict__ B11, float* __restrict__ Y11,
    int M1)
{
    __shared__ float xsT[32][132];   // [k][row], stride 132 keeps 16B align
    __shared__ float ws[32][260];    // [k][col 0..255]; 0-127=W0, 128-255=W1

    const float *X, *W0, *B0, *W1, *B1;
    float *Y0, *Y1;
    int M, bid;
    if ((int)blockIdx.x < nb0) {
        X = X0; W0 = W00; B0 = B00; Y0 = Y00; W1 = W01; B1 = B01; Y1 = Y01;
        M = M0; bid = blockIdx.x;
    } else {
        X = X1; W0 = W10; B0 = B10; Y0 = Y10; W1 = W11; B1 = B11; Y1 = Y11;
        M = M1; bid = blockIdx.x - nb0;
    }

    const int tid = threadIdx.x;
    const int tx  = tid & 31;        // col group: c0 = tx*4 (in each half)
    const int ty  = tid >> 5;        // row group: r0 = ty*8
    const int c0  = tx * 4;
    const int r0  = ty * 8;
    const int m0  = bid * 128;

    float acc[8][8];
#pragma unroll
    for (int i = 0; i < 8; ++i)
#pragma unroll
        for (int j = 0; j < 8; ++j) acc[i][j] = 0.0f;

    for (int kc = 0; kc < 128; kc += 32) {
        // X tile: 128 rows x 32 k (1024 float4, 2/thread), transpose into xsT
#pragma unroll
        for (int j = 0; j < 2; ++j) {
            int idx = tid + j * 512;
            int row = idx >> 3;
            int kq  = (idx & 7) * 4;
            float4 v = make_float4(0.f, 0.f, 0.f, 0.f);
            if (m0 + row < M)
                v = *(const float4*)&X[(size_t)(m0 + row) * 128 + kc + kq];
            xsT[kq + 0][row] = v.x;
            xsT[kq + 1][row] = v.y;
            xsT[kq + 2][row] = v.z;
            xsT[kq + 3][row] = v.w;
        }
        // W tiles: 32 k x 256 n (2048 float4, 4/thread)
#pragma unroll
        for (int j = 0; j < 4; ++j) {
            int idx = tid + j * 512;
            int k = idx >> 6;
            int q = (idx & 63) * 4;
            float4 v = (q < 128)
                ? *(const float4*)&W0[(size_t)(kc + k) * 128 + q]
                : *(const float4*)&W1[(size_t)(kc + k) * 128 + (q - 128)];
            *(float4*)&ws[k][q] = v;
        }
        __syncthreads();

#pragma unroll
        for (int k = 0; k < 32; ++k) {
            float4 a0 = *(const float4*)&xsT[k][r0];
            float4 a1 = *(const float4*)&xsT[k][r0 + 4];
            float4 b0 = *(const float4*)&ws[k][c0];
            float4 b1 = *(const float4*)&ws[k][c0 + 128];
            float ar[8] = { a0.x, a0.y, a0.z, a0.w, a1.x, a1.y, a1.z, a1.w };
#pragma unroll
            for (int i = 0; i < 8; ++i) {
                float a = ar[i];
                acc[i][0] += a * b0.x; acc[i][1] += a * b0.y;
                acc[i][2] += a * b0.z; acc[i][3] += a * b0.w;
                acc[i][4] += a * b1.x; acc[i][5] += a * b1.y;
                acc[i][6] += a * b1.z; acc[i][7] += a * b1.w;
            }
        }
        __syncthreads();
    }

    float4 q0 = *(const float4*)&B0[c0];
    float4 q1 = *(const float4*)&B1[c0];
#pragma unroll
    for (int i = 0; i < 8; ++i) {
        int row = m0 + r0 + i;
        if (row < M) {
            *(float4*)&Y0[(size_t)row * 128 + c0] = make_float4(
                acc[i][0] + q0.x, acc[i][1] + q0.y, acc[i][2] + q0.z, acc[i][3] + q0.w);
            *(float4*)&Y1[(size_t)row * 128 + c0] = make_float4(
                acc[i][4] + q1.x, acc[i][5] + q1.y, acc[i][6] + q1.z, acc[i][7] + q1.w);
        }
    }
}

// ---------- fused GAT, both directions in one grid; one wave per dst node ---
// No running max: logits = att.lrelu(xi+xj) with att ~ N(0,1/64) => |p| <~ 8,
// exp(p) safe in fp32 (overflow only at p>85). alpha = exp(p)/sum exp(p) is
// mathematically identical to the max-subtracted reference. Removing the
// rescale kills the serial loop-carried chain -> the 2-edge unroll overlaps.
__global__ __launch_bounds__(256) void k_gat2(
    const float* __restrict__ xl_a, const float* __restrict__ xr_a,
    const float* __restrict__ att_a, const float* __restrict__ bias_a,
    float* __restrict__ out_a,
    const float* __restrict__ xl_b, const float* __restrict__ xr_b,
    const float* __restrict__ att_b, const float* __restrict__ bias_b,
    float* __restrict__ out_b,
    const int* __restrict__ rowptr, const int* __restrict__ srcs,
    int n_a, int n_all)
{
    int wave = (blockIdx.x * 256 + threadIdx.x) >> 6;
    if (wave >= n_all) return;
    const int lane = threadIdx.x & 63;
    const int h = lane >> 5;
    const int j = lane & 31;
    const int c0 = h * 64 + j;
    const int c1 = c0 + 32;

    const float *xl, *xr, *att, *bias;
    float* out;
    int d;
    if (wave < n_a) { xl = xl_a; xr = xr_a; att = att_a; bias = bias_a; out = out_a; d = wave; }
    else            { xl = xl_b; xr = xr_b; att = att_b; bias = bias_b; out = out_b; d = wave - n_a; }

    const int base = rowptr[wave];
    const int end  = rowptr[wave + 1];
    if (base == end) {                       // empty segment -> out = bias
        if (lane < 32) {
            out[(size_t)d * 64 + j]      = bias[j];
            out[(size_t)d * 64 + j + 32] = bias[j + 32];
        }
        return;
    }

    const float xi0 = xr[(size_t)d * 128 + c0];
    const float xi1 = xr[(size_t)d * 128 + c1];
    const float at0 = att[c0];
    const float at1 = att[c1];

    float den = 0.f, a0 = 0.f, a1 = 0.f;
    int k = base;
    for (; k + 1 < end; k += 2) {
        int s0 = srcs[k];
        int s1 = srcs[k + 1];
        const float* xp0 = xl + (size_t)s0 * 128;
        const float* xp1 = xl + (size_t)s1 * 128;
        float x00 = xp0[c0], x01 = xp0[c1];
        float x10 = xp1[c0], x11 = xp1[c1];
        float e00 = xi0 + x00, e01 = xi1 + x01;
        float e10 = xi0 + x10, e11 = xi1 + x11;
        e00 = e00 >= 0.f ? e00 : 0.2f * e00;
        e01 = e01 >= 0.f ? e01 : 0.2f * e01;
        e10 = e10 >= 0.f ? e10 : 0.2f * e10;
        e11 = e11 >= 0.f ? e11 : 0.2f * e11;
        float p0 = e00 * at0 + e01 * at1;
        float p1 = e10 * at0 + e11 * at1;
        // two independent butterflies, interleaved for ILP
        p0 += __shfl_xor(p0, 1, 64);  p1 += __shfl_xor(p1, 1, 64);
        p0 += __shfl_xor(p0, 2, 64);  p1 += __shfl_xor(p1, 2, 64);
        p0 += __shfl_xor(p0, 4, 64);  p1 += __shfl_xor(p1, 4, 64);
        p0 += __shfl_xor(p0, 8, 64);  p1 += __shfl_xor(p1, 8, 64);
        p0 += __shfl_xor(p0, 16, 64); p1 += __shfl_xor(p1, 16, 64);
        float w0 = __expf(p0);
        float w1 = __expf(p1);
        den += w0 + w1;
        a0  += w0 * x00 + w1 * x10;
        a1  += w0 * x01 + w1 * x11;
    }
    if (k < end) {                            // odd tail
        int s0 = srcs[k];
        const float* xp0 = xl + (size_t)s0 * 128;
        float x00 = xp0[c0], x01 = xp0[c1];
        float e00 = xi0 + x00, e01 = xi1 + x01;
        e00 = e00 >= 0.f ? e00 : 0.2f * e00;
        e01 = e01 >= 0.f ? e01 : 0.2f * e01;
        float p0 = e00 * at0 + e01 * at1;
        p0 += __shfl_xor(p0, 1, 64);
        p0 += __shfl_xor(p0, 2, 64);
        p0 += __shfl_xor(p0, 4, 64);
        p0 += __shfl_xor(p0, 8, 64);
        p0 += __shfl_xor(p0, 16, 64);
        float w0 = __expf(p0);
        den += w0;
        a0  += w0 * x00;
        a1  += w0 * x01;
    }

    float inv = 1.0f / (den + 1e-16f);
    float r0 = a0 * inv;
    float r1 = a1 * inv;
    float q0 = __shfl_xor(r0, 32, 64);        // other head's same channel
    float q1 = __shfl_xor(r1, 32, 64);
    if (lane < 32) {
        out[(size_t)d * 64 + j]      = 0.5f * (r0 + q0) + bias[j];
        out[(size_t)d * 64 + j + 32] = 0.5f * (r1 + q1) + bias[j + 32];
    }
}

extern "C" void kernel_launch(void* const* d_in, const int* in_sizes, int n_in,
                              void* d_out, int out_size, void* d_ws, size_t ws_size,
                              hipStream_t stream)
{
    const float* x_user   = (const float*)d_in[0];
    const float* x_item   = (const float*)d_in[1];
    const int*   src_u2i  = (const int*)d_in[2];
    const int*   dst_u2i  = (const int*)d_in[3];
    const int*   src_i2u  = (const int*)d_in[4];
    const int*   dst_i2u  = (const int*)d_in[5];
    const float* Wl_u2i   = (const float*)d_in[6];
    const float* bl_u2i   = (const float*)d_in[7];
    const float* Wr_u2i   = (const float*)d_in[8];
    const float* br_u2i   = (const float*)d_in[9];
    const float* att_u2i  = (const float*)d_in[10];
    const float* bias_u2i = (const float*)d_in[11];
    const float* Wl_i2u   = (const float*)d_in[12];
    const float* bl_i2u   = (const float*)d_in[13];
    const float* Wr_i2u   = (const float*)d_in[14];
    const float* br_i2u   = (const float*)d_in[15];
    const float* att_i2u  = (const float*)d_in[16];
    const float* bias_i2u = (const float*)d_in[17];

    const int n_user = in_sizes[0] / 128;
    const int n_item = in_sizes[1] / 128;
    const int E      = in_sizes[2];
    const int n_all  = n_item + n_user;      // rowptr: [0,n_item)=u2i, rest=i2u

    float* out_user = (float*)d_out;                   // [n_user,64]
    float* out_item = out_user + (size_t)n_user * 64;  // [n_item,64]

    char* w = (char*)d_ws;
    float* xl_u2i = (float*)w; w += (size_t)n_user * 128 * 4;
    float* xr_u2i = (float*)w; w += (size_t)n_item * 128 * 4;
    float* xl_i2u = (float*)w; w += (size_t)n_item * 128 * 4;
    float* xr_i2u = (float*)w; w += (size_t)n_user * 128 * 4;
    int* srcs_all   = (int*)w; w += (size_t)2 * E * 4;
    int* rowptr_all = (int*)w; w += (size_t)(n_all + 1) * 4;
    int* cnt_all    = (int*)w; w += (size_t)n_all * 4;     // reused as cursor
    int* bsum       = (int*)w; w += (size_t)SCAN_B * 4;

    const int nb = (n_all + SCAN_B - 1) / SCAN_B;

    // ---- CSR build (both directions share one scan) ----
    k_zero<<<(n_all + 255) / 256, 256, 0, stream>>>(cnt_all, n_all);
    k_hist<<<(2 * E + 255) / 256, 256, 0, stream>>>(dst_u2i, dst_i2u, cnt_all, n_item, E);
    k_scan1<<<nb, SCAN_B, 0, stream>>>(cnt_all, n_all, rowptr_all, bsum);
    k_scan2<<<1, SCAN_B, 0, stream>>>(bsum, nb);
    k_scan3<<<(n_all + 255) / 256, 256, 0, stream>>>(rowptr_all, cnt_all, bsum, n_all, 2 * E);
    k_fill<<<(2 * E + 255) / 256, 256, 0, stream>>>(
        src_u2i, dst_u2i, src_i2u, dst_i2u, cnt_all, srcs_all, n_item, E);

    // ---- node linear transforms: both node types, one dispatch ----
    const int nb_user = (n_user + 127) / 128;
    const int nb_item = (n_item + 127) / 128;
    gemm_dual<<<nb_user + nb_item, 512, 0, stream>>>(
        x_user, Wl_u2i, bl_u2i, xl_u2i, Wr_i2u, br_i2u, xr_i2u, n_user, nb_user,
        x_item, Wl_i2u, bl_i2u, xl_i2u, Wr_u2i, br_u2i, xr_u2i, n_item);

    // ---- fused single-pass GAT, both directions in one launch ----
    k_gat2<<<(n_all + 3) / 4, 256, 0, stream>>>(
        xl_u2i, xr_u2i, att_u2i, bias_u2i, out_item,
        xl_i2u, xr_i2u, att_i2u, bias_i2u, out_user,
        rowptr_all, srcs_all, n_item, n_all);
}

// Round 9
// 465.861 us; speedup vs baseline: 1.0678x; 1.0678x over previous
//
#include <hip/hip_runtime.h>

#define SCAN_B 1024

// ---------------- CSR build ----------------
__global__ __launch_bounds__(256) void k_zero(int* __restrict__ cnt, int n) {
    int i = blockIdx.x * 256 + threadIdx.x;
    if (i < n) cnt[i] = 0;
}

__global__ __launch_bounds__(256) void k_hist(
    const int* __restrict__ dst_a, const int* __restrict__ dst_b,
    int* __restrict__ cnt, int n_a, int E)
{
    int i = blockIdx.x * 256 + threadIdx.x;
    if (i >= 2 * E) return;
    int idx = (i < E) ? dst_a[i] : (n_a + dst_b[i - E]);
    atomicAdd(&cnt[idx], 1);
}

__global__ __launch_bounds__(SCAN_B) void k_scan1(
    const int* __restrict__ cnt, int n, int* __restrict__ rowptr, int* __restrict__ bsum)
{
    __shared__ int tmp[SCAN_B];
    int i = blockIdx.x * SCAN_B + threadIdx.x;
    int v = (i < n) ? cnt[i] : 0;
    tmp[threadIdx.x] = v;
    __syncthreads();
    for (int off = 1; off < SCAN_B; off <<= 1) {
        int t = (threadIdx.x >= (unsigned)off) ? tmp[threadIdx.x - off] : 0;
        __syncthreads();
        tmp[threadIdx.x] += t;
        __syncthreads();
    }
    if (i < n) rowptr[i] = tmp[threadIdx.x] - v;   // exclusive
    if (threadIdx.x == SCAN_B - 1) bsum[blockIdx.x] = tmp[threadIdx.x];
}

__global__ __launch_bounds__(SCAN_B) void k_scan2(int* __restrict__ bsum, int nb) {
    __shared__ int tmp[SCAN_B];
    int i = threadIdx.x;
    int v = (i < nb) ? bsum[i] : 0;
    tmp[i] = v;
    __syncthreads();
    for (int off = 1; off < SCAN_B; off <<= 1) {
        int t = (i >= off) ? tmp[i - off] : 0;
        __syncthreads();
        tmp[i] += t;
        __syncthreads();
    }
    if (i < nb) bsum[i] = tmp[i] - v;              // exclusive
}

__global__ __launch_bounds__(256) void k_scan3(
    int* __restrict__ rowptr, int* __restrict__ cursor,
    const int* __restrict__ bsum, int n, int total)
{
    int i = blockIdx.x * 256 + threadIdx.x;
    if (i < n) {
        int r = rowptr[i] + bsum[i / SCAN_B];
        rowptr[i] = r;
        cursor[i] = r;
    }
    if (i == 0) rowptr[n] = total;
}

__global__ __launch_bounds__(256) void k_fill(
    const int* __restrict__ src_a, const int* __restrict__ dst_a,
    const int* __restrict__ src_b, const int* __restrict__ dst_b,
    int* __restrict__ cursor, int* __restrict__ sorted_src, int n_a, int E)
{
    int i = blockIdx.x * 256 + threadIdx.x;
    if (i >= 2 * E) return;
    int idx, s;
    if (i < E) { idx = dst_a[i];            s = src_a[i]; }
    else       { idx = n_a + dst_b[i - E];  s = src_b[i - E]; }
    int pos = atomicAdd(&cursor[idx], 1);
    sorted_src[pos] = s;
}

// ---------- dual GEMM, R5-proven layout (conflict-free, 58 TF), merged grid -
// Per block: 64 rows x 256 cols (128 -> Y0 via W0, 128 -> Y1 via W1).
// 256 threads, per-thread 4x16, K chunked by 32. Blocks [0,nb0) = problem 0
// (X0: user), rest = problem 1 (X1: item).
__global__ __launch_bounds__(256) void gemm128x2(
    const float* __restrict__ X0,
    const float* __restrict__ W00, const float* __restrict__ B00, float* __restrict__ Y00,
    const float* __restrict__ W01, const float* __restrict__ B01, float* __restrict__ Y01,
    int M0, int nb0,
    const float* __restrict__ X1,
    const float* __restrict__ W10, const float* __restrict__ B10, float* __restrict__ Y10,
    const float* __restrict__ W11, const float* __restrict__ B11, float* __restrict__ Y11,
    int M1)
{
    __shared__ float xs[64][36];     // +4 pad: conflict-free (measured 0 in R5)
    __shared__ float ws[32][256];    // cols 0-127 = W0, 128-255 = W1

    const float *X, *W0, *B0, *W1, *B1;
    float *Y0, *Y1;
    int M, bid;
    if ((int)blockIdx.x < nb0) {
        X = X0; W0 = W00; B0 = B00; Y0 = Y00; W1 = W01; B1 = B01; Y1 = Y01;
        M = M0; bid = blockIdx.x;
    } else {
        X = X1; W0 = W10; B0 = B10; Y0 = Y10; W1 = W11; B1 = B11; Y1 = Y11;
        M = M1; bid = blockIdx.x - nb0;
    }

    const int tid = threadIdx.x;
    const int m0  = bid * 64;
    const int r0  = (tid >> 4) * 4;   // 0..60
    const int c0  = (tid & 15) * 4;   // 0..60; covers c0, c0+64 (Y0) and +128, +192 (Y1)

    float acc[4][16];
#pragma unroll
    for (int i = 0; i < 4; ++i)
#pragma unroll
        for (int j = 0; j < 16; ++j) acc[i][j] = 0.0f;

    for (int kc = 0; kc < 128; kc += 32) {
        // X tile: 64 rows x 32 k (512 float4, 2 per thread)
#pragma unroll
        for (int i = 0; i < 2; ++i) {
            int f = tid + i * 256;
            int row = f >> 3;
            int kq  = (f & 7) * 4;
            float4 v = make_float4(0.f, 0.f, 0.f, 0.f);
            if (m0 + row < M)
                v = *(const float4*)&X[(size_t)(m0 + row) * 128 + kc + kq];
            *(float4*)&xs[row][kq] = v;
        }
        // W tiles: 32 k x 256 n (2048 float4, 8 per thread)
#pragma unroll
        for (int i = 0; i < 8; ++i) {
            int f = tid + i * 256;
            int k = f >> 6;
            int q = (f & 63) * 4;
            float4 v = (q < 128)
                ? *(const float4*)&W0[(size_t)(kc + k) * 128 + q]
                : *(const float4*)&W1[(size_t)(kc + k) * 128 + (q - 128)];
            *(float4*)&ws[k][q] = v;
        }
        __syncthreads();

#pragma unroll
        for (int k = 0; k < 32; k += 4) {
            float4 a0 = *(const float4*)&xs[r0 + 0][k];
            float4 a1 = *(const float4*)&xs[r0 + 1][k];
            float4 a2 = *(const float4*)&xs[r0 + 2][k];
            float4 a3 = *(const float4*)&xs[r0 + 3][k];
#pragma unroll
            for (int kk = 0; kk < 4; ++kk) {
                float4 b0 = *(const float4*)&ws[k + kk][c0];
                float4 b1 = *(const float4*)&ws[k + kk][c0 + 64];
                float4 b2 = *(const float4*)&ws[k + kk][c0 + 128];
                float4 b3 = *(const float4*)&ws[k + kk][c0 + 192];
                float av[4] = { ((const float*)&a0)[kk], ((const float*)&a1)[kk],
                                ((const float*)&a2)[kk], ((const float*)&a3)[kk] };
#pragma unroll
                for (int i = 0; i < 4; ++i) {
                    float a = av[i];
                    acc[i][0]  += a * b0.x; acc[i][1]  += a * b0.y;
                    acc[i][2]  += a * b0.z; acc[i][3]  += a * b0.w;
                    acc[i][4]  += a * b1.x; acc[i][5]  += a * b1.y;
                    acc[i][6]  += a * b1.z; acc[i][7]  += a * b1.w;
                    acc[i][8]  += a * b2.x; acc[i][9]  += a * b2.y;
                    acc[i][10] += a * b2.z; acc[i][11] += a * b2.w;
                    acc[i][12] += a * b3.x; acc[i][13] += a * b3.y;
                    acc[i][14] += a * b3.z; acc[i][15] += a * b3.w;
                }
            }
        }
        __syncthreads();
    }

    float4 p00 = *(const float4*)&B0[c0];
    float4 p01 = *(const float4*)&B0[c0 + 64];
    float4 p10 = *(const float4*)&B1[c0];
    float4 p11 = *(const float4*)&B1[c0 + 64];
#pragma unroll
    for (int i = 0; i < 4; ++i) {
        int row = m0 + r0 + i;
        if (row < M) {
            *(float4*)&Y0[(size_t)row * 128 + c0] = make_float4(
                acc[i][0] + p00.x, acc[i][1] + p00.y, acc[i][2] + p00.z, acc[i][3] + p00.w);
            *(float4*)&Y0[(size_t)row * 128 + c0 + 64] = make_float4(
                acc[i][4] + p01.x, acc[i][5] + p01.y, acc[i][6] + p01.z, acc[i][7] + p01.w);
            *(float4*)&Y1[(size_t)row * 128 + c0] = make_float4(
                acc[i][8] + p10.x, acc[i][9] + p10.y, acc[i][10] + p10.z, acc[i][11] + p10.w);
            *(float4*)&Y1[(size_t)row * 128 + c0 + 64] = make_float4(
                acc[i][12] + p11.x, acc[i][13] + p11.y, acc[i][14] + p11.z, acc[i][15] + p11.w);
        }
    }
}

// ---------- fused GAT, both directions in one grid; one wave per dst node ---
// No running max: logits = att.lrelu(xi+xj) with att ~ N(0,1/64) => |p| <~ 8,
// exp(p) safe in fp32. alpha = exp(p)/sum exp(p) identical to max-subtracted
// reference. No serial rescale chain -> the 2-edge unroll overlaps.
__global__ __launch_bounds__(256) void k_gat2(
    const float* __restrict__ xl_a, const float* __restrict__ xr_a,
    const float* __restrict__ att_a, const float* __restrict__ bias_a,
    float* __restrict__ out_a,
    const float* __restrict__ xl_b, const float* __restrict__ xr_b,
    const float* __restrict__ att_b, const float* __restrict__ bias_b,
    float* __restrict__ out_b,
    const int* __restrict__ rowptr, const int* __restrict__ srcs,
    int n_a, int n_all)
{
    int wave = (blockIdx.x * 256 + threadIdx.x) >> 6;
    if (wave >= n_all) return;
    const int lane = threadIdx.x & 63;
    const int h = lane >> 5;
    const int j = lane & 31;
    const int c0 = h * 64 + j;
    const int c1 = c0 + 32;

    const float *xl, *xr, *att, *bias;
    float* out;
    int d;
    if (wave < n_a) { xl = xl_a; xr = xr_a; att = att_a; bias = bias_a; out = out_a; d = wave; }
    else            { xl = xl_b; xr = xr_b; att = att_b; bias = bias_b; out = out_b; d = wave - n_a; }

    const int base = rowptr[wave];
    const int end  = rowptr[wave + 1];
    if (base == end) {                       // empty segment -> out = bias
        if (lane < 32) {
            out[(size_t)d * 64 + j]      = bias[j];
            out[(size_t)d * 64 + j + 32] = bias[j + 32];
        }
        return;
    }

    const float xi0 = xr[(size_t)d * 128 + c0];
    const float xi1 = xr[(size_t)d * 128 + c1];
    const float at0 = att[c0];
    const float at1 = att[c1];

    float den = 0.f, a0 = 0.f, a1 = 0.f;
    int k = base;
    for (; k + 1 < end; k += 2) {
        int s0 = srcs[k];
        int s1 = srcs[k + 1];
        const float* xp0 = xl + (size_t)s0 * 128;
        const float* xp1 = xl + (size_t)s1 * 128;
        float x00 = xp0[c0], x01 = xp0[c1];
        float x10 = xp1[c0], x11 = xp1[c1];
        float e00 = xi0 + x00, e01 = xi1 + x01;
        float e10 = xi0 + x10, e11 = xi1 + x11;
        e00 = e00 >= 0.f ? e00 : 0.2f * e00;
        e01 = e01 >= 0.f ? e01 : 0.2f * e01;
        e10 = e10 >= 0.f ? e10 : 0.2f * e10;
        e11 = e11 >= 0.f ? e11 : 0.2f * e11;
        float p0 = e00 * at0 + e01 * at1;
        float p1 = e10 * at0 + e11 * at1;
        // two independent butterflies, interleaved for ILP
        p0 += __shfl_xor(p0, 1, 64);  p1 += __shfl_xor(p1, 1, 64);
        p0 += __shfl_xor(p0, 2, 64);  p1 += __shfl_xor(p1, 2, 64);
        p0 += __shfl_xor(p0, 4, 64);  p1 += __shfl_xor(p1, 4, 64);
        p0 += __shfl_xor(p0, 8, 64);  p1 += __shfl_xor(p1, 8, 64);
        p0 += __shfl_xor(p0, 16, 64); p1 += __shfl_xor(p1, 16, 64);
        float w0 = __expf(p0);
        float w1 = __expf(p1);
        den += w0 + w1;
        a0  += w0 * x00 + w1 * x10;
        a1  += w0 * x01 + w1 * x11;
    }
    if (k < end) {                            // odd tail
        int s0 = srcs[k];
        const float* xp0 = xl + (size_t)s0 * 128;
        float x00 = xp0[c0], x01 = xp0[c1];
        float e00 = xi0 + x00, e01 = xi1 + x01;
        e00 = e00 >= 0.f ? e00 : 0.2f * e00;
        e01 = e01 >= 0.f ? e01 : 0.2f * e01;
        float p0 = e00 * at0 + e01 * at1;
        p0 += __shfl_xor(p0, 1, 64);
        p0 += __shfl_xor(p0, 2, 64);
        p0 += __shfl_xor(p0, 4, 64);
        p0 += __shfl_xor(p0, 8, 64);
        p0 += __shfl_xor(p0, 16, 64);
        float w0 = __expf(p0);
        den += w0;
        a0  += w0 * x00;
        a1  += w0 * x01;
    }

    float inv = 1.0f / (den + 1e-16f);
    float r0 = a0 * inv;
    float r1 = a1 * inv;
    float q0 = __shfl_xor(r0, 32, 64);        // other head's same channel
    float q1 = __shfl_xor(r1, 32, 64);
    if (lane < 32) {
        out[(size_t)d * 64 + j]      = 0.5f * (r0 + q0) + bias[j];
        out[(size_t)d * 64 + j + 32] = 0.5f * (r1 + q1) + bias[j + 32];
    }
}

extern "C" void kernel_launch(void* const* d_in, const int* in_sizes, int n_in,
                              void* d_out, int out_size, void* d_ws, size_t ws_size,
                              hipStream_t stream)
{
    const float* x_user   = (const float*)d_in[0];
    const float* x_item   = (const float*)d_in[1];
    const int*   src_u2i  = (const int*)d_in[2];
    const int*   dst_u2i  = (const int*)d_in[3];
    const int*   src_i2u  = (const int*)d_in[4];
    const int*   dst_i2u  = (const int*)d_in[5];
    const float* Wl_u2i   = (const float*)d_in[6];
    const float* bl_u2i   = (const float*)d_in[7];
    const float* Wr_u2i   = (const float*)d_in[8];
    const float* br_u2i   = (const float*)d_in[9];
    const float* att_u2i  = (const float*)d_in[10];
    const float* bias_u2i = (const float*)d_in[11];
    const float* Wl_i2u   = (const float*)d_in[12];
    const float* bl_i2u   = (const float*)d_in[13];
    const float* Wr_i2u   = (const float*)d_in[14];
    const float* br_i2u   = (const float*)d_in[15];
    const float* att_i2u  = (const float*)d_in[16];
    const float* bias_i2u = (const float*)d_in[17];

    const int n_user = in_sizes[0] / 128;
    const int n_item = in_sizes[1] / 128;
    const int E      = in_sizes[2];
    const int n_all  = n_item + n_user;      // rowptr: [0,n_item)=u2i, rest=i2u

    float* out_user = (float*)d_out;                   // [n_user,64]
    float* out_item = out_user + (size_t)n_user * 64;  // [n_item,64]

    char* w = (char*)d_ws;
    float* xl_u2i = (float*)w; w += (size_t)n_user * 128 * 4;
    float* xr_u2i = (float*)w; w += (size_t)n_item * 128 * 4;
    float* xl_i2u = (float*)w; w += (size_t)n_item * 128 * 4;
    float* xr_i2u = (float*)w; w += (size_t)n_user * 128 * 4;
    int* srcs_all   = (int*)w; w += (size_t)2 * E * 4;
    int* rowptr_all = (int*)w; w += (size_t)(n_all + 1) * 4;
    int* cnt_all    = (int*)w; w += (size_t)n_all * 4;     // reused as cursor
    int* bsum       = (int*)w; w += (size_t)SCAN_B * 4;

    const int nb = (n_all + SCAN_B - 1) / SCAN_B;

    // ---- CSR build (both directions share one scan) ----
    k_zero<<<(n_all + 255) / 256, 256, 0, stream>>>(cnt_all, n_all);
    k_hist<<<(2 * E + 255) / 256, 256, 0, stream>>>(dst_u2i, dst_i2u, cnt_all, n_item, E);
    k_scan1<<<nb, SCAN_B, 0, stream>>>(cnt_all, n_all, rowptr_all, bsum);
    k_scan2<<<1, SCAN_B, 0, stream>>>(bsum, nb);
    k_scan3<<<(n_all + 255) / 256, 256, 0, stream>>>(rowptr_all, cnt_all, bsum, n_all, 2 * E);
    k_fill<<<(2 * E + 255) / 256, 256, 0, stream>>>(
        src_u2i, dst_u2i, src_i2u, dst_i2u, cnt_all, srcs_all, n_item, E);

    // ---- node linear transforms: both node types, one dispatch, R5 layout --
    const int nb_user = (n_user + 63) / 64;
    const int nb_item = (n_item + 63) / 64;
    gemm128x2<<<nb_user + nb_item, 256, 0, stream>>>(
        x_user, Wl_u2i, bl_u2i, xl_u2i, Wr_i2u, br_i2u, xr_i2u, n_user, nb_user,
        x_item, Wl_i2u, bl_i2u, xl_i2u, Wr_u2i, br_u2i, xr_u2i, n_item);

    // ---- fused single-pass GAT, both directions in one launch ----
    k_gat2<<<(n_all + 3) / 4, 256, 0, stream>>>(
        xl_u2i, xr_u2i, att_u2i, bias_u2i, out_item,
        xl_i2u, xr_i2u, att_i2u, bias_i2u, out_user,
        rowptr_all, srcs_all, n_item, n_all);
}

// Round 10
// 448.679 us; speedup vs baseline: 1.1087x; 1.0383x over previous
//
#include <hip/hip_runtime.h>

#define SCAN_B 1024

// ---------------- CSR build ----------------
__global__ __launch_bounds__(256) void k_zero(int* __restrict__ cnt, int n) {
    int i = blockIdx.x * 256 + threadIdx.x;
    if (i < n) cnt[i] = 0;
}

__global__ __launch_bounds__(256) void k_hist(
    const int* __restrict__ dst_a, const int* __restrict__ dst_b,
    int* __restrict__ cnt, int n_a, int E)
{
    int i = blockIdx.x * 256 + threadIdx.x;
    if (i >= 2 * E) return;
    int idx = (i < E) ? dst_a[i] : (n_a + dst_b[i - E]);
    atomicAdd(&cnt[idx], 1);
}

__global__ __launch_bounds__(SCAN_B) void k_scan1(
    const int* __restrict__ cnt, int n, int* __restrict__ rowptr, int* __restrict__ bsum)
{
    __shared__ int tmp[SCAN_B];
    int i = blockIdx.x * SCAN_B + threadIdx.x;
    int v = (i < n) ? cnt[i] : 0;
    tmp[threadIdx.x] = v;
    __syncthreads();
    for (int off = 1; off < SCAN_B; off <<= 1) {
        int t = (threadIdx.x >= (unsigned)off) ? tmp[threadIdx.x - off] : 0;
        __syncthreads();
        tmp[threadIdx.x] += t;
        __syncthreads();
    }
    if (i < n) rowptr[i] = tmp[threadIdx.x] - v;   // exclusive
    if (threadIdx.x == SCAN_B - 1) bsum[blockIdx.x] = tmp[threadIdx.x];
}

__global__ __launch_bounds__(SCAN_B) void k_scan2(int* __restrict__ bsum, int nb) {
    __shared__ int tmp[SCAN_B];
    int i = threadIdx.x;
    int v = (i < nb) ? bsum[i] : 0;
    tmp[i] = v;
    __syncthreads();
    for (int off = 1; off < SCAN_B; off <<= 1) {
        int t = (i >= off) ? tmp[i - off] : 0;
        __syncthreads();
        tmp[i] += t;
        __syncthreads();
    }
    if (i < nb) bsum[i] = tmp[i] - v;              // exclusive
}

__global__ __launch_bounds__(256) void k_scan3(
    int* __restrict__ rowptr, int* __restrict__ cursor,
    const int* __restrict__ bsum, int n, int total)
{
    int i = blockIdx.x * 256 + threadIdx.x;
    if (i < n) {
        int r = rowptr[i] + bsum[i / SCAN_B];
        rowptr[i] = r;
        cursor[i] = r;
    }
    if (i == 0) rowptr[n] = total;
}

__global__ __launch_bounds__(256) void k_fill(
    const int* __restrict__ src_a, const int* __restrict__ dst_a,
    const int* __restrict__ src_b, const int* __restrict__ dst_b,
    int* __restrict__ cursor, int* __restrict__ sorted_src, int n_a, int E)
{
    int i = blockIdx.x * 256 + threadIdx.x;
    if (i >= 2 * E) return;
    int idx, s;
    if (i < E) { idx = dst_a[i];            s = src_a[i]; }
    else       { idx = n_a + dst_b[i - E];  s = src_b[i - E]; }
    int pos = atomicAdd(&cursor[idx], 1);
    sorted_src[pos] = s;
}

// ---------- dual GEMM, merged grid, K-chunk 16 for occupancy ----------------
// Per block: 64 rows x 256 cols (128 -> Y0 via W0, 128 -> Y1 via W1).
// 256 threads, per-thread 4x16. LDS = 21.5 KB (was 42 KB): xs[64][20] +
// ws[16][256] -> 4 blocks/CU resident (VGPR-capped), vs 3 before.
// Access patterns identical to the R5-proven conflict-free layout.
__global__ __launch_bounds__(256) void gemm128x2(
    const float* __restrict__ X0,
    const float* __restrict__ W00, const float* __restrict__ B00, float* __restrict__ Y00,
    const float* __restrict__ W01, const float* __restrict__ B01, float* __restrict__ Y01,
    int M0, int nb0,
    const float* __restrict__ X1,
    const float* __restrict__ W10, const float* __restrict__ B10, float* __restrict__ Y10,
    const float* __restrict__ W11, const float* __restrict__ B11, float* __restrict__ Y11,
    int M1)
{
    __shared__ float xs[64][20];     // 16-k chunk, +4 pad, 16B-aligned rows
    __shared__ float ws[16][256];    // cols 0-127 = W0, 128-255 = W1

    const float *X, *W0, *B0, *W1, *B1;
    float *Y0, *Y1;
    int M, bid;
    if ((int)blockIdx.x < nb0) {
        X = X0; W0 = W00; B0 = B00; Y0 = Y00; W1 = W01; B1 = B01; Y1 = Y01;
        M = M0; bid = blockIdx.x;
    } else {
        X = X1; W0 = W10; B0 = B10; Y0 = Y10; W1 = W11; B1 = B11; Y1 = Y11;
        M = M1; bid = blockIdx.x - nb0;
    }

    const int tid = threadIdx.x;
    const int m0  = bid * 64;
    const int r0  = (tid >> 4) * 4;   // 0..60
    const int c0  = (tid & 15) * 4;   // 0..60; covers c0, c0+64 (Y0) and +128, +192 (Y1)

    float acc[4][16];
#pragma unroll
    for (int i = 0; i < 4; ++i)
#pragma unroll
        for (int j = 0; j < 16; ++j) acc[i][j] = 0.0f;

    for (int kc = 0; kc < 128; kc += 16) {
        // X tile: 64 rows x 16 k (256 float4, 1 per thread)
        {
            int row = tid >> 2;
            int kq  = (tid & 3) * 4;
            float4 v = make_float4(0.f, 0.f, 0.f, 0.f);
            if (m0 + row < M)
                v = *(const float4*)&X[(size_t)(m0 + row) * 128 + kc + kq];
            *(float4*)&xs[row][kq] = v;
        }
        // W tiles: 16 k x 256 n (1024 float4, 4 per thread)
#pragma unroll
        for (int i = 0; i < 4; ++i) {
            int f = tid + i * 256;
            int k = f >> 6;
            int q = (f & 63) * 4;
            float4 v = (q < 128)
                ? *(const float4*)&W0[(size_t)(kc + k) * 128 + q]
                : *(const float4*)&W1[(size_t)(kc + k) * 128 + (q - 128)];
            *(float4*)&ws[k][q] = v;
        }
        __syncthreads();

#pragma unroll
        for (int k = 0; k < 16; k += 4) {
            float4 a0 = *(const float4*)&xs[r0 + 0][k];
            float4 a1 = *(const float4*)&xs[r0 + 1][k];
            float4 a2 = *(const float4*)&xs[r0 + 2][k];
            float4 a3 = *(const float4*)&xs[r0 + 3][k];
#pragma unroll
            for (int kk = 0; kk < 4; ++kk) {
                float4 b0 = *(const float4*)&ws[k + kk][c0];
                float4 b1 = *(const float4*)&ws[k + kk][c0 + 64];
                float4 b2 = *(const float4*)&ws[k + kk][c0 + 128];
                float4 b3 = *(const float4*)&ws[k + kk][c0 + 192];
                float av[4] = { ((const float*)&a0)[kk], ((const float*)&a1)[kk],
                                ((const float*)&a2)[kk], ((const float*)&a3)[kk] };
#pragma unroll
                for (int i = 0; i < 4; ++i) {
                    float a = av[i];
                    acc[i][0]  += a * b0.x; acc[i][1]  += a * b0.y;
                    acc[i][2]  += a * b0.z; acc[i][3]  += a * b0.w;
                    acc[i][4]  += a * b1.x; acc[i][5]  += a * b1.y;
                    acc[i][6]  += a * b1.z; acc[i][7]  += a * b1.w;
                    acc[i][8]  += a * b2.x; acc[i][9]  += a * b2.y;
                    acc[i][10] += a * b2.z; acc[i][11] += a * b2.w;
                    acc[i][12] += a * b3.x; acc[i][13] += a * b3.y;
                    acc[i][14] += a * b3.z; acc[i][15] += a * b3.w;
                }
            }
        }
        __syncthreads();
    }

    float4 p00 = *(const float4*)&B0[c0];
    float4 p01 = *(const float4*)&B0[c0 + 64];
    float4 p10 = *(const float4*)&B1[c0];
    float4 p11 = *(const float4*)&B1[c0 + 64];
#pragma unroll
    for (int i = 0; i < 4; ++i) {
        int row = m0 + r0 + i;
        if (row < M) {
            *(float4*)&Y0[(size_t)row * 128 + c0] = make_float4(
                acc[i][0] + p00.x, acc[i][1] + p00.y, acc[i][2] + p00.z, acc[i][3] + p00.w);
            *(float4*)&Y0[(size_t)row * 128 + c0 + 64] = make_float4(
                acc[i][4] + p01.x, acc[i][5] + p01.y, acc[i][6] + p01.z, acc[i][7] + p01.w);
            *(float4*)&Y1[(size_t)row * 128 + c0] = make_float4(
                acc[i][8] + p10.x, acc[i][9] + p10.y, acc[i][10] + p10.z, acc[i][11] + p10.w);
            *(float4*)&Y1[(size_t)row * 128 + c0 + 64] = make_float4(
                acc[i][12] + p11.x, acc[i][13] + p11.y, acc[i][14] + p11.z, acc[i][15] + p11.w);
        }
    }
}

// ---------- fused GAT, both directions in one grid; one wave per dst node ---
// Lane layout: h = lane>>5, j = lane&31; lane covers ADJACENT channels
// (h*64+2j, h*64+2j+1) -> all gathers are float2 (one b64 load per edge per
// lane, wave reads the full 512B row in one instruction). lrelu = fmax(e,.2e).
// No running max (|logit| <~ 8, fp32-safe; identical alpha).
__global__ __launch_bounds__(256) void k_gat2(
    const float* __restrict__ xl_a, const float* __restrict__ xr_a,
    const float* __restrict__ att_a, const float* __restrict__ bias_a,
    float* __restrict__ out_a,
    const float* __restrict__ xl_b, const float* __restrict__ xr_b,
    const float* __restrict__ att_b, const float* __restrict__ bias_b,
    float* __restrict__ out_b,
    const int* __restrict__ rowptr, const int* __restrict__ srcs,
    int n_a, int n_all)
{
    int wave = (blockIdx.x * 256 + threadIdx.x) >> 6;
    if (wave >= n_all) return;
    const int lane = threadIdx.x & 63;
    const int h = lane >> 5;
    const int j = lane & 31;
    const int ch = h * 64 + 2 * j;           // channel pair (ch, ch+1) of head h

    const float *xl, *xr, *att, *bias;
    float* out;
    int d;
    if (wave < n_a) { xl = xl_a; xr = xr_a; att = att_a; bias = bias_a; out = out_a; d = wave; }
    else            { xl = xl_b; xr = xr_b; att = att_b; bias = bias_b; out = out_b; d = wave - n_a; }

    const int base = rowptr[wave];
    const int end  = rowptr[wave + 1];
    if (base == end) {                       // empty segment -> out = bias
        if (lane < 32) {
            float2 bv = *(const float2*)&bias[2 * j];
            *(float2*)&out[(size_t)d * 64 + 2 * j] = bv;
        }
        return;
    }

    const float2 xi = *(const float2*)&xr[(size_t)d * 128 + ch];
    const float2 at = *(const float2*)&att[ch];

    float den = 0.f, a0 = 0.f, a1 = 0.f;
    int k = base;
    for (; k + 1 < end; k += 2) {
        int s0 = srcs[k];
        int s1 = srcs[k + 1];
        float2 x0 = *(const float2*)&xl[(size_t)s0 * 128 + ch];
        float2 x1 = *(const float2*)&xl[(size_t)s1 * 128 + ch];
        float e00 = xi.x + x0.x, e01 = xi.y + x0.y;
        float e10 = xi.x + x1.x, e11 = xi.y + x1.y;
        e00 = fmaxf(e00, 0.2f * e00);
        e01 = fmaxf(e01, 0.2f * e01);
        e10 = fmaxf(e10, 0.2f * e10);
        e11 = fmaxf(e11, 0.2f * e11);
        float p0 = e00 * at.x + e01 * at.y;
        float p1 = e10 * at.x + e11 * at.y;
        // two independent butterflies, interleaved for ILP (32-lane halves)
        p0 += __shfl_xor(p0, 1, 64);  p1 += __shfl_xor(p1, 1, 64);
        p0 += __shfl_xor(p0, 2, 64);  p1 += __shfl_xor(p1, 2, 64);
        p0 += __shfl_xor(p0, 4, 64);  p1 += __shfl_xor(p1, 4, 64);
        p0 += __shfl_xor(p0, 8, 64);  p1 += __shfl_xor(p1, 8, 64);
        p0 += __shfl_xor(p0, 16, 64); p1 += __shfl_xor(p1, 16, 64);
        float w0 = __expf(p0);
        float w1 = __expf(p1);
        den += w0 + w1;
        a0  += w0 * x0.x + w1 * x1.x;
        a1  += w0 * x0.y + w1 * x1.y;
    }
    if (k < end) {                            // odd tail
        int s0 = srcs[k];
        float2 x0 = *(const float2*)&xl[(size_t)s0 * 128 + ch];
        float e00 = xi.x + x0.x, e01 = xi.y + x0.y;
        e00 = fmaxf(e00, 0.2f * e00);
        e01 = fmaxf(e01, 0.2f * e01);
        float p0 = e00 * at.x + e01 * at.y;
        p0 += __shfl_xor(p0, 1, 64);
        p0 += __shfl_xor(p0, 2, 64);
        p0 += __shfl_xor(p0, 4, 64);
        p0 += __shfl_xor(p0, 8, 64);
        p0 += __shfl_xor(p0, 16, 64);
        float w0 = __expf(p0);
        den += w0;
        a0  += w0 * x0.x;
        a1  += w0 * x0.y;
    }

    float inv = 1.0f / (den + 1e-16f);
    float r0 = a0 * inv;                      // channel ch   of head h
    float r1 = a1 * inv;                      // channel ch+1 of head h
    float q0 = __shfl_xor(r0, 32, 64);        // other head, same channels
    float q1 = __shfl_xor(r1, 32, 64);
    if (lane < 32) {
        float2 bv = *(const float2*)&bias[2 * j];
        float2 o = make_float2(0.5f * (r0 + q0) + bv.x,
                               0.5f * (r1 + q1) + bv.y);
        *(float2*)&out[(size_t)d * 64 + 2 * j] = o;
    }
}

extern "C" void kernel_launch(void* const* d_in, const int* in_sizes, int n_in,
                              void* d_out, int out_size, void* d_ws, size_t ws_size,
                              hipStream_t stream)
{
    const float* x_user   = (const float*)d_in[0];
    const float* x_item   = (const float*)d_in[1];
    const int*   src_u2i  = (const int*)d_in[2];
    const int*   dst_u2i  = (const int*)d_in[3];
    const int*   src_i2u  = (const int*)d_in[4];
    const int*   dst_i2u  = (const int*)d_in[5];
    const float* Wl_u2i   = (const float*)d_in[6];
    const float* bl_u2i   = (const float*)d_in[7];
    const float* Wr_u2i   = (const float*)d_in[8];
    const float* br_u2i   = (const float*)d_in[9];
    const float* att_u2i  = (const float*)d_in[10];
    const float* bias_u2i = (const float*)d_in[11];
    const float* Wl_i2u   = (const float*)d_in[12];
    const float* bl_i2u   = (const float*)d_in[13];
    const float* Wr_i2u   = (const float*)d_in[14];
    const float* br_i2u   = (const float*)d_in[15];
    const float* att_i2u  = (const float*)d_in[16];
    const float* bias_i2u = (const float*)d_in[17];

    const int n_user = in_sizes[0] / 128;
    const int n_item = in_sizes[1] / 128;
    const int E      = in_sizes[2];
    const int n_all  = n_item + n_user;      // rowptr: [0,n_item)=u2i, rest=i2u

    float* out_user = (float*)d_out;                   // [n_user,64]
    float* out_item = out_user + (size_t)n_user * 64;  // [n_item,64]

    char* w = (char*)d_ws;
    float* xl_u2i = (float*)w; w += (size_t)n_user * 128 * 4;
    float* xr_u2i = (float*)w; w += (size_t)n_item * 128 * 4;
    float* xl_i2u = (float*)w; w += (size_t)n_item * 128 * 4;
    float* xr_i2u = (float*)w; w += (size_t)n_user * 128 * 4;
    int* srcs_all   = (int*)w; w += (size_t)2 * E * 4;
    int* rowptr_all = (int*)w; w += (size_t)(n_all + 1) * 4;
    int* cnt_all    = (int*)w; w += (size_t)n_all * 4;     // reused as cursor
    int* bsum       = (int*)w; w += (size_t)SCAN_B * 4;

    const int nb = (n_all + SCAN_B - 1) / SCAN_B;

    // ---- CSR build (both directions share one scan) ----
    k_zero<<<(n_all + 255) / 256, 256, 0, stream>>>(cnt_all, n_all);
    k_hist<<<(2 * E + 255) / 256, 256, 0, stream>>>(dst_u2i, dst_i2u, cnt_all, n_item, E);
    k_scan1<<<nb, SCAN_B, 0, stream>>>(cnt_all, n_all, rowptr_all, bsum);
    k_scan2<<<1, SCAN_B, 0, stream>>>(bsum, nb);
    k_scan3<<<(n_all + 255) / 256, 256, 0, stream>>>(rowptr_all, cnt_all, bsum, n_all, 2 * E);
    k_fill<<<(2 * E + 255) / 256, 256, 0, stream>>>(
        src_u2i, dst_u2i, src_i2u, dst_i2u, cnt_all, srcs_all, n_item, E);

    // ---- node linear transforms: both node types, one dispatch ----
    const int nb_user = (n_user + 63) / 64;
    const int nb_item = (n_item + 63) / 64;
    gemm128x2<<<nb_user + nb_item, 256, 0, stream>>>(
        x_user, Wl_u2i, bl_u2i, xl_u2i, Wr_i2u, br_i2u, xr_i2u, n_user, nb_user,
        x_item, Wl_i2u, bl_i2u, xl_i2u, Wr_u2i, br_u2i, xr_u2i, n_item);

    // ---- fused single-pass GAT, both directions in one launch ----
    k_gat2<<<(n_all + 3) / 4, 256, 0, stream>>>(
        xl_u2i, xr_u2i, att_u2i, bias_u2i, out_item,
        xl_i2u, xr_i2u, att_i2u, bias_i2u, out_user,
        rowptr_all, srcs_all, n_item, n_all);
}